// Round 6
// baseline (495.214 us; speedup 1.0000x reference)
//
#include <hip/hip_runtime.h>
#include <cstdint>

#define N 8192
#define FIN 256
#define FOUT 128
#define ALPHA 0.2f
#define JP 4                 // j-split: 4 slices
#define JSL (N / JP)         // 2048 j's per block
#define NSTEP (JSL / 32)     // 64 k-steps of 32 j's

typedef unsigned short u16;
typedef __attribute__((ext_vector_type(8))) short short8;
typedef __attribute__((ext_vector_type(4))) float floatx4;

__device__ __forceinline__ u16 bf16_rne(float f) {
  uint32_t u = __float_as_uint(f);
  u += 0x7fff + ((u >> 16) & 1);
  return (u16)(u >> 16);
}

// ---------------------------------------------------------------------------
// Kernel 1: h = x@W (fp32); write hT3 (bf16) tiled [jb][nt][m*4+q][8] (each
// k_gat b-frag load = contiguous 1 KB per wave); src = h@a1, dst = h@a2.
// ---------------------------------------------------------------------------
__global__ __launch_bounds__(256) void k_proj(const float* __restrict__ x,
                                              const float* __restrict__ W,
                                              const float* __restrict__ a,
                                              u16* __restrict__ hT3,
                                              float* __restrict__ srcv,
                                              float* __restrict__ dstv) {
  __shared__ float xs[8 * FIN];                     // 8 KB
  __shared__ float partS[4][4], partD[4][4];
  const int t = threadIdx.x;
  const int R0 = blockIdx.x * 8;

  const float4* xv = (const float4*)(x + (size_t)R0 * FIN);
  float4* xsv = (float4*)xs;
  xsv[t] = xv[t];
  xsv[t + 256] = xv[t + 256];
  __syncthreads();

  const int c  = t & 127;           // output column
  const int rg = (t >> 7) * 4;      // row group base (wave-uniform)

  float acc[4] = {0.f, 0.f, 0.f, 0.f};
  float wa[4], wb[4];
  #pragma unroll
  for (int j = 0; j < 4; ++j) wa[j] = W[j * FOUT + c];
  #pragma unroll
  for (int j = 0; j < 4; ++j) wb[j] = W[(4 + j) * FOUT + c];

  for (int k4 = 0; k4 < FIN / 4; ++k4) {
    float wc[4];
    #pragma unroll
    for (int j = 0; j < 4; ++j) { wc[j] = wa[j]; wa[j] = wb[j]; }
    const int kn = (k4 + 2 < FIN / 4) ? k4 + 2 : k4;
    #pragma unroll
    for (int j = 0; j < 4; ++j) wb[j] = W[(kn * 4 + j) * FOUT + c];
    #pragma unroll
    for (int i = 0; i < 4; ++i) {
      const float4 xq = *(const float4*)&xs[(rg + i) * FIN + k4 * 4];
      acc[i] += xq.x * wc[0] + xq.y * wc[1] + xq.z * wc[2] + xq.w * wc[3];
    }
  }

  {
    const int j = R0 + rg;                 // 4 consecutive j in one q-octet
    const int jb = j >> 5, q = (j >> 3) & 3, jj = j & 7;
    const int m = c & 15, nt = c >> 4;
    union { u16 u[4]; uint2 v; } pk;
    #pragma unroll
    for (int i = 0; i < 4; ++i) pk.u[i] = bf16_rne(acc[i]);
    *(uint2*)(hT3 + (size_t)(((jb * 8 + nt) * 64) + (m * 4 + q)) * 8 + jj) = pk.v;
  }

  const float a1 = a[c], a2 = a[FOUT + c];
  float s4[4], d4[4];
  #pragma unroll
  for (int i = 0; i < 4; ++i) { s4[i] = acc[i] * a1; d4[i] = acc[i] * a2; }
  #pragma unroll
  for (int off = 32; off > 0; off >>= 1) {
    #pragma unroll
    for (int i = 0; i < 4; ++i) {
      s4[i] += __shfl_down(s4[i], off);
      d4[i] += __shfl_down(d4[i], off);
    }
  }
  const int wv = t >> 6, lane = t & 63;
  if (lane == 0) {
    #pragma unroll
    for (int i = 0; i < 4; ++i) { partS[wv][i] = s4[i]; partD[wv][i] = d4[i]; }
  }
  __syncthreads();
  if (t < 16) {
    const int i = t & 3, rg2 = (t >> 2) & 1, which = t >> 3;
    if (which == 0) srcv[R0 + rg2 * 4 + i] = partS[rg2*2][i] + partS[rg2*2+1][i];
    else            dstv[R0 + rg2 * 4 + i] = partD[rg2*2][i] + partD[rg2*2+1][i];
  }
}

// ---------------------------------------------------------------------------
// Kernel 2: wave-independent fused GAT, L1-shared b-tiles.
// All 4 waves of a block work the SAME 2048-j slice (so each step's 8-KB hT3
// tile is read 4x with 3 L1 hits) on DIFFERENT 16-row strips (64 rows/block,
// disjoint -> no reduction). adj/dst prefetched distance-4 in named register
// quad-buffers (vmcnt retires in issue order, so bf waits drag the youngest
// outstanding HBM refill; distance-4 + cheap L1 bf-hits bound the exposure
// to ~1 step). Strict per-step order: bf loads -> refill -> p-VALU -> MFMA.
// Grid: bm(0..127) | jp<<7 (0..3) = 512 blocks.
// ---------------------------------------------------------------------------
__global__ __launch_bounds__(256, 2) void k_gat(const int* __restrict__ adj,
                                                const u16* __restrict__ hT3,
                                                const float* __restrict__ srcv,
                                                const float* __restrict__ dstv,
                                                float* __restrict__ P,
                                                float* __restrict__ lp) {
  const int t = threadIdx.x;
  const int wv = t >> 6, lane = t & 63;
  const int q = lane >> 4, m = lane & 15;
  const int bm = blockIdx.x & 127;
  const int jp = blockIdx.x >> 7;         // 0..3 (partial index)
  const int R0 = (bm * 4 + wv) * 16;      // this wave's 16-row strip
  const int j0 = jp * JSL;

  const float srcm = srcv[R0 + m];
  const int*   adjp = adj + (size_t)(R0 + m) * N + j0 + q * 8;
  const float* dstp = dstv + j0 + q * 8;
  const u16*   hpl  = hT3 + (size_t)(j0 >> 5) * 4096 + (size_t)(m * 4 + q) * 8;

  floatx4 acc[8];
  #pragma unroll
  for (int nt = 0; nt < 8; ++nt) acc[nt] = (floatx4){0.f, 0.f, 0.f, 0.f};
  float lsum = 0.f;

  // prologue: fill four named prefetch buffers (steps 0..3)
  int4   aA0 = *(const int4*)(adjp),        aA1 = *(const int4*)(adjp + 4);
  float4 dA0 = *(const float4*)(dstp),      dA1 = *(const float4*)(dstp + 4);
  int4   aB0 = *(const int4*)(adjp + 32),   aB1 = *(const int4*)(adjp + 36);
  float4 dB0 = *(const float4*)(dstp + 32), dB1 = *(const float4*)(dstp + 36);
  int4   aC0 = *(const int4*)(adjp + 64),   aC1 = *(const int4*)(adjp + 68);
  float4 dC0 = *(const float4*)(dstp + 64), dC1 = *(const float4*)(dstp + 68);
  int4   aD0 = *(const int4*)(adjp + 96),   aD1 = *(const int4*)(adjp + 100);
  float4 dD0 = *(const float4*)(dstp + 96), dD1 = *(const float4*)(dstp + 100);

  #define GAT_STEP(I, A0_, A1_, D0_, D1_, NX)                                  \
  {                                                                            \
    /* (1) b-frags: 8 x contiguous 1 KB (L1-shared across the 4 waves) */      \
    const u16* hpi = hpl + (size_t)(I) * 4096;                                 \
    short8 bf0 = *(const short8*)(hpi);                                        \
    short8 bf1 = *(const short8*)(hpi + 512);                                  \
    short8 bf2 = *(const short8*)(hpi + 1024);                                 \
    short8 bf3 = *(const short8*)(hpi + 1536);                                 \
    short8 bf4 = *(const short8*)(hpi + 2048);                                 \
    short8 bf5 = *(const short8*)(hpi + 2560);                                 \
    short8 bf6 = *(const short8*)(hpi + 3072);                                 \
    short8 bf7 = *(const short8*)(hpi + 3584);                                 \
    const int4   cA0 = A0_, cA1 = A1_;                                         \
    const float4 cD0 = D0_, cD1 = D1_;                                         \
    /* (2) refill this buffer for step I+4 */                                  \
    A0_ = *(const int4*)(adjp + (NX) * 32);                                    \
    A1_ = *(const int4*)(adjp + (NX) * 32 + 4);                                \
    D0_ = *(const float4*)(dstp + (NX) * 32);                                  \
    D1_ = *(const float4*)(dstp + (NX) * 32 + 4);                              \
    /* (3) p-compute */                                                        \
    const int   ai[8] = {cA0.x, cA0.y, cA0.z, cA0.w, cA1.x, cA1.y, cA1.z, cA1.w}; \
    const float df[8] = {cD0.x, cD0.y, cD0.z, cD0.w, cD1.x, cD1.y, cD1.z, cD1.w}; \
    union { u16 u[8]; short8 s; } pk;                                          \
    _Pragma("unroll")                                                          \
    for (int e = 0; e < 8; ++e) {                                              \
      float v = srcm + df[e];                                                  \
      v = fmaxf(v, ALPHA * v);                                                 \
      const float p = ai[e] > 0 ? __expf(v) : 0.f;                             \
      lsum += p;                                                               \
      pk.u[e] = bf16_rne(p);                                                   \
    }                                                                          \
    /* (4) MFMAs */                                                            \
    acc[0] = __builtin_amdgcn_mfma_f32_16x16x32_bf16(pk.s, bf0, acc[0], 0, 0, 0); \
    acc[1] = __builtin_amdgcn_mfma_f32_16x16x32_bf16(pk.s, bf1, acc[1], 0, 0, 0); \
    acc[2] = __builtin_amdgcn_mfma_f32_16x16x32_bf16(pk.s, bf2, acc[2], 0, 0, 0); \
    acc[3] = __builtin_amdgcn_mfma_f32_16x16x32_bf16(pk.s, bf3, acc[3], 0, 0, 0); \
    acc[4] = __builtin_amdgcn_mfma_f32_16x16x32_bf16(pk.s, bf4, acc[4], 0, 0, 0); \
    acc[5] = __builtin_amdgcn_mfma_f32_16x16x32_bf16(pk.s, bf5, acc[5], 0, 0, 0); \
    acc[6] = __builtin_amdgcn_mfma_f32_16x16x32_bf16(pk.s, bf6, acc[6], 0, 0, 0); \
    acc[7] = __builtin_amdgcn_mfma_f32_16x16x32_bf16(pk.s, bf7, acc[7], 0, 0, 0); \
  }

  for (int i = 0; i < NSTEP; i += 4) {
    const int nxA = (i + 4 < NSTEP) ? i + 4 : i;
    GAT_STEP(i, aA0, aA1, dA0, dA1, nxA)
    const int nxB = (i + 5 < NSTEP) ? i + 5 : i + 1;
    GAT_STEP(i + 1, aB0, aB1, dB0, dB1, nxB)
    const int nxC = (i + 6 < NSTEP) ? i + 6 : i + 2;
    GAT_STEP(i + 2, aC0, aC1, dC0, dC1, nxC)
    const int nxD = (i + 7 < NSTEP) ? i + 7 : i + 3;
    GAT_STEP(i + 3, aD0, aD1, dD0, dD1, nxD)
  }
  #undef GAT_STEP

  // row-sum: reduce over the 4 q-lanes sharing row m
  lsum += __shfl_xor(lsum, 16);
  lsum += __shfl_xor(lsum, 32);
  if (lane < 16) lp[(size_t)jp * N + R0 + lane] = lsum;

  // partial store (C/D layout: row = q*4+ri, col = nt*16+m), strips disjoint
  float* Pp = P + ((size_t)jp * N + R0) * FOUT;
  #pragma unroll
  for (int nt = 0; nt < 8; ++nt)
    #pragma unroll
    for (int ri = 0; ri < 4; ++ri)
      Pp[(size_t)(q * 4 + ri) * FOUT + nt * 16 + m] = acc[nt][ri];
}

// ---------------------------------------------------------------------------
// Kernel 3: sum 4 partials, normalize by row-sum. ~20 MB traffic.
// ---------------------------------------------------------------------------
__global__ __launch_bounds__(256) void k_norm(const float* __restrict__ P,
                                              const float* __restrict__ lp,
                                              float* __restrict__ out) {
  const int idx = blockIdx.x * 256 + threadIdx.x;   // 0 .. N*FOUT/4-1
  const int rr = idx >> 5;
  const int c4 = (idx & 31) * 4;
  const float l = lp[rr] + lp[N + rr] + lp[2 * N + rr] + lp[3 * N + rr];
  const float inv = 1.0f / l;
  float4 s = {0.f, 0.f, 0.f, 0.f};
  #pragma unroll
  for (int jp = 0; jp < 4; ++jp) {
    const float4 p = *(const float4*)(P + ((size_t)jp * N + rr) * FOUT + c4);
    s.x += p.x; s.y += p.y; s.z += p.z; s.w += p.w;
  }
  s.x *= inv; s.y *= inv; s.z *= inv; s.w *= inv;
  *(float4*)(out + (size_t)rr * FOUT + c4) = s;
}

extern "C" void kernel_launch(void* const* d_in, const int* in_sizes, int n_in,
                              void* d_out, int out_size, void* d_ws, size_t ws_size,
                              hipStream_t stream) {
  const float* x   = (const float*)d_in[0];
  const int*   adj = (const int*)d_in[1];
  const float* W   = (const float*)d_in[2];
  const float* a   = (const float*)d_in[3];
  float* out = (float*)d_out;

  char* ws = (char*)d_ws;
  u16*   hT3  = (u16*)ws;     ws += (size_t)FOUT * N * sizeof(u16);            // 2 MB
  float* srcv = (float*)ws;   ws += (size_t)N * sizeof(float);
  float* dstv = (float*)ws;   ws += (size_t)N * sizeof(float);
  float* P    = (float*)ws;   ws += (size_t)JP * N * FOUT * sizeof(float);     // 16 MB
  float* lp   = (float*)ws;   ws += (size_t)JP * N * sizeof(float);

  k_proj<<<N / 8, 256, 0, stream>>>(x, W, a, hT3, srcv, dstv);
  k_gat <<<128 * JP, 256, 0, stream>>>(adj, hT3, srcv, dstv, P, lp);
  k_norm<<<(N * FOUT / 4) / 256, 256, 0, stream>>>(P, lp, out);
}

// Round 7
// 435.841 us; speedup vs baseline: 1.1362x; 1.1362x over previous
//
#include <hip/hip_runtime.h>
#include <cstdint>

#define N 8192
#define FIN 256
#define FOUT 128
#define ALPHA 0.2f
#define JP 4                  // j-split
#define JSL (N / JP)          // 2048 j per block
#define TJ 64                 // j-tile
#define NTILE (JSL / TJ)      // 32 tiles
#define RB 32                 // rows per block
#define SST 72                // S stride in u16 (16B-aligned rows, baseline banks)

typedef unsigned short u16;
typedef __attribute__((ext_vector_type(8))) short short8;
typedef __attribute__((ext_vector_type(4))) float floatx4;

__device__ __forceinline__ u16 bf16_rne(float f) {
  uint32_t u = __float_as_uint(f);
  u += 0x7fff + ((u >> 16) & 1);
  return (u16)(u >> 16);
}

// async global->LDS DMA, 16 B per lane, whole wave. LDS dest = uniform base
// + lane*16 (m104: wave-uniform base, lane-contiguous — layout must match).
__device__ __forceinline__ void gl_lds16(const void* g, void* l) {
  __builtin_amdgcn_global_load_lds(
      (const __attribute__((address_space(1))) void*)g,
      (__attribute__((address_space(3))) void*)l, 16, 0, 0);
}

// ---------------------------------------------------------------------------
// Kernel 1: h = x@W (fp32); hT3 bf16 tiled [jb][nt][m*4+q][8] (1-KB chunks,
// DMA- and wave-contiguous); src = h@a1, dst = h@a2.  (unchanged)
// ---------------------------------------------------------------------------
__global__ __launch_bounds__(256) void k_proj(const float* __restrict__ x,
                                              const float* __restrict__ W,
                                              const float* __restrict__ a,
                                              u16* __restrict__ hT3,
                                              float* __restrict__ srcv,
                                              float* __restrict__ dstv) {
  __shared__ float xs[8 * FIN];                     // 8 KB
  __shared__ float partS[4][4], partD[4][4];
  const int t = threadIdx.x;
  const int R0 = blockIdx.x * 8;

  const float4* xv = (const float4*)(x + (size_t)R0 * FIN);
  float4* xsv = (float4*)xs;
  xsv[t] = xv[t];
  xsv[t + 256] = xv[t + 256];
  __syncthreads();

  const int c  = t & 127;
  const int rg = (t >> 7) * 4;

  float acc[4] = {0.f, 0.f, 0.f, 0.f};
  float wa[4], wb[4];
  #pragma unroll
  for (int j = 0; j < 4; ++j) wa[j] = W[j * FOUT + c];
  #pragma unroll
  for (int j = 0; j < 4; ++j) wb[j] = W[(4 + j) * FOUT + c];

  for (int k4 = 0; k4 < FIN / 4; ++k4) {
    float wc[4];
    #pragma unroll
    for (int j = 0; j < 4; ++j) { wc[j] = wa[j]; wa[j] = wb[j]; }
    const int kn = (k4 + 2 < FIN / 4) ? k4 + 2 : k4;
    #pragma unroll
    for (int j = 0; j < 4; ++j) wb[j] = W[(kn * 4 + j) * FOUT + c];
    #pragma unroll
    for (int i = 0; i < 4; ++i) {
      const float4 xq = *(const float4*)&xs[(rg + i) * FIN + k4 * 4];
      acc[i] += xq.x * wc[0] + xq.y * wc[1] + xq.z * wc[2] + xq.w * wc[3];
    }
  }

  {
    const int j = R0 + rg;
    const int jb = j >> 5, q = (j >> 3) & 3, jj = j & 7;
    const int m = c & 15, nt = c >> 4;
    union { u16 u[4]; uint2 v; } pk;
    #pragma unroll
    for (int i = 0; i < 4; ++i) pk.u[i] = bf16_rne(acc[i]);
    *(uint2*)(hT3 + (size_t)(((jb * 8 + nt) * 64) + (m * 4 + q)) * 8 + jj) = pk.v;
  }

  const float a1 = a[c], a2 = a[FOUT + c];
  float s4[4], d4[4];
  #pragma unroll
  for (int i = 0; i < 4; ++i) { s4[i] = acc[i] * a1; d4[i] = acc[i] * a2; }
  #pragma unroll
  for (int off = 32; off > 0; off >>= 1) {
    #pragma unroll
    for (int i = 0; i < 4; ++i) {
      s4[i] += __shfl_down(s4[i], off);
      d4[i] += __shfl_down(d4[i], off);
    }
  }
  const int wv = t >> 6, lane = t & 63;
  if (lane == 0) {
    #pragma unroll
    for (int i = 0; i < 4; ++i) { partS[wv][i] = s4[i]; partD[wv][i] = d4[i]; }
  }
  __syncthreads();
  if (t < 16) {
    const int i = t & 3, rg2 = (t >> 2) & 1, which = t >> 3;
    if (which == 0) srcv[R0 + rg2 * 4 + i] = partS[rg2*2][i] + partS[rg2*2+1][i];
    else            dstv[R0 + rg2 * 4 + i] = partD[rg2*2][i] + partD[rg2*2+1][i];
  }
}

// ---------------------------------------------------------------------------
// Kernel 2: m97-style fused GAT. Block = 32 rows x 128 cols over a 2048-j
// slice, 64-j tiles, double-buffered hT stage via global_load_lds (DMA queue
// absorbs global latency — rounds 3-6 coupled it into the MFMA chain and
// plateaued ~200 us at <13% on every pipe). Per tile: B1(drain) -> DMA next
// tile + reg-prefetch adj/dst (1-tile cover) -> p-phase -> S in LDS -> B2 ->
// MFMA (A from S, B from hS via ds_read_b128). 1024 blocks, 4/CU (37 KB LDS).
// ---------------------------------------------------------------------------
__global__ __launch_bounds__(256, 4) void k_gat(const int* __restrict__ adj,
                                                const u16* __restrict__ hT3,
                                                const float* __restrict__ srcv,
                                                const float* __restrict__ dstv,
                                                float* __restrict__ P,
                                                float* __restrict__ lp) {
  __shared__ u16 hS[2][8192];      // 2 x 16 KB staged hT tiles
  __shared__ u16 S[RB * SST];      // 4.6 KB p-tile (bf16)
  const int t = threadIdx.x;
  const int wv = t >> 6, lane = t & 63;
  const int q = lane >> 4, m = lane & 15;
  const int bm = blockIdx.x & 255;
  const int jp = blockIdx.x >> 8;
  const int R0 = bm * RB;
  const int j0 = jp * JSL;

  // p-phase mapping: thread -> (row pr, 8 cols at pc)
  const int pr = t >> 3;
  const int pc = (t & 7) * 8;
  const float srcr = srcv[R0 + pr];
  const int*   adjp = adj + (size_t)(R0 + pr) * N + j0 + pc;
  const float* dstp = dstv + j0 + pc;

  // MFMA mapping: wave -> (row-half rh, col-half ch)
  const int rh = wv & 1, ch = wv >> 1;
  const int Lq = m * 4 + q;                      // hT3/hS lane index

  floatx4 acc[4];
  #pragma unroll
  for (int nt = 0; nt < 4; ++nt) acc[nt] = (floatx4){0.f, 0.f, 0.f, 0.f};
  float lsum = 0.f;

  // DMA one tile (16 KB = 16 chunks of 1 KB); wave wv stages chunks wv*4..+4
  const size_t jb00 = (size_t)(j0 >> 5);         // first global jb of slice
  #define STAGE(I, BUF)                                                        \
  {                                                                            \
    _Pragma("unroll")                                                          \
    for (int cc = 0; cc < 4; ++cc) {                                           \
      const int kc = wv * 4 + cc;               /* 0..15 */                    \
      const int jbl = kc >> 3, nt_ = kc & 7;                                   \
      const u16* src = hT3 + ((jb00 + (size_t)(I) * 2 + jbl) * 8 + nt_) * 512  \
                       + (size_t)lane * 8;                                     \
      gl_lds16(src, &hS[BUF][kc * 512]);                                       \
    }                                                                          \
  }

  // prologue: stage tile 0 into buf 0; register-prefetch tile 0 adj/dst
  STAGE(0, 0)
  int4   aC0 = *(const int4*)(adjp),     aC1 = *(const int4*)(adjp + 4);
  float4 dC0 = *(const float4*)(dstp),   dC1 = *(const float4*)(dstp + 4);

  int buf = 0;
  for (int i = 0; i < NTILE; ++i) {
    __syncthreads();   // B1: DMA(i)+prefetch complete; S & hS[buf^1] free

    // DMA tile i+1 into the other buffer; reg-prefetch adj/dst for tile i+1
    const int nx = (i + 1 < NTILE) ? i + 1 : i;
    if (i + 1 < NTILE) STAGE(i + 1, buf ^ 1)
    int4   aN0 = *(const int4*)(adjp + nx * TJ);
    int4   aN1 = *(const int4*)(adjp + nx * TJ + 4);
    float4 dN0 = *(const float4*)(dstp + nx * TJ);
    float4 dN1 = *(const float4*)(dstp + nx * TJ + 4);

    // p-phase: 8 p-values/thread from prefetched regs -> S (bf16)
    {
      const int   ai[8] = {aC0.x, aC0.y, aC0.z, aC0.w, aC1.x, aC1.y, aC1.z, aC1.w};
      const float df[8] = {dC0.x, dC0.y, dC0.z, dC0.w, dC1.x, dC1.y, dC1.z, dC1.w};
      union { u16 u[8]; short8 s; } pk;
      #pragma unroll
      for (int e = 0; e < 8; ++e) {
        float v = srcr + df[e];
        v = fmaxf(v, ALPHA * v);
        const float p = ai[e] > 0 ? __expf(v) : 0.f;
        lsum += p;
        pk.u[e] = bf16_rne(p);
      }
      *(short8*)&S[pr * SST + pc] = pk.s;
    }

    __syncthreads();   // B2: S ready (hS[buf] ready since B1)

    // MFMA: A-frags from S, B-frags from hS[buf]
    {
      const short8 a0 = *(const short8*)&S[(rh * 16 + m) * SST + q * 8];
      const short8 a1 = *(const short8*)&S[(rh * 16 + m) * SST + 32 + q * 8];
      #pragma unroll
      for (int nt = 0; nt < 4; ++nt) {
        const short8 b0 = *(const short8*)&hS[buf][(0 * 8 + ch * 4 + nt) * 512 + Lq * 8];
        const short8 b1 = *(const short8*)&hS[buf][(1 * 8 + ch * 4 + nt) * 512 + Lq * 8];
        acc[nt] = __builtin_amdgcn_mfma_f32_16x16x32_bf16(a0, b0, acc[nt], 0, 0, 0);
        acc[nt] = __builtin_amdgcn_mfma_f32_16x16x32_bf16(a1, b1, acc[nt], 0, 0, 0);
      }
    }

    aC0 = aN0; aC1 = aN1; dC0 = dN0; dC1 = dN1;
    buf ^= 1;
  }
  #undef STAGE

  // row-sum: reduce over the 8 threads sharing row pr (aligned groups)
  lsum += __shfl_down(lsum, 4);
  lsum += __shfl_down(lsum, 2);
  lsum += __shfl_down(lsum, 1);
  if ((t & 7) == 0) lp[(size_t)jp * N + R0 + pr] = lsum;

  // partial store (C/D layout: row = q*4+ri, col = nt*16+m)
  float* Pp = P + ((size_t)jp * N + R0 + rh * 16) * FOUT + ch * 64;
  #pragma unroll
  for (int nt = 0; nt < 4; ++nt)
    #pragma unroll
    for (int ri = 0; ri < 4; ++ri)
      Pp[(size_t)(q * 4 + ri) * FOUT + nt * 16 + m] = acc[nt][ri];
}

// ---------------------------------------------------------------------------
// Kernel 3: sum JP partials, normalize by row-sum. ~36 MB traffic.
// ---------------------------------------------------------------------------
__global__ __launch_bounds__(256) void k_norm(const float* __restrict__ P,
                                              const float* __restrict__ lp,
                                              float* __restrict__ out) {
  const int idx = blockIdx.x * 256 + threadIdx.x;   // 0 .. N*FOUT/4-1
  const int rr = idx >> 5;
  const int c4 = (idx & 31) * 4;
  float l = 0.f;
  #pragma unroll
  for (int j = 0; j < JP; ++j) l += lp[j * N + rr];
  const float inv = 1.0f / l;
  float4 s = {0.f, 0.f, 0.f, 0.f};
  #pragma unroll
  for (int j = 0; j < JP; ++j) {
    const float4 p = *(const float4*)(P + ((size_t)j * N + rr) * FOUT + c4);
    s.x += p.x; s.y += p.y; s.z += p.z; s.w += p.w;
  }
  s.x *= inv; s.y *= inv; s.z *= inv; s.w *= inv;
  *(float4*)(out + (size_t)rr * FOUT + c4) = s;
}

extern "C" void kernel_launch(void* const* d_in, const int* in_sizes, int n_in,
                              void* d_out, int out_size, void* d_ws, size_t ws_size,
                              hipStream_t stream) {
  const float* x   = (const float*)d_in[0];
  const int*   adj = (const int*)d_in[1];
  const float* W   = (const float*)d_in[2];
  const float* a   = (const float*)d_in[3];
  float* out = (float*)d_out;

  char* ws = (char*)d_ws;
  u16*   hT3  = (u16*)ws;     ws += (size_t)FOUT * N * sizeof(u16);            // 2 MB
  float* srcv = (float*)ws;   ws += (size_t)N * sizeof(float);
  float* dstv = (float*)ws;   ws += (size_t)N * sizeof(float);
  float* P    = (float*)ws;   ws += (size_t)JP * N * FOUT * sizeof(float);     // 16 MB
  float* lp   = (float*)ws;   ws += (size_t)JP * N * sizeof(float);

  k_proj<<<N / 8, 256, 0, stream>>>(x, W, a, hT3, srcv, dstv);
  k_gat <<<256 * JP, 256, 0, stream>>>(adj, hT3, srcv, dstv, P, lp);
  k_norm<<<(N * FOUT / 4) / 256, 256, 0, stream>>>(P, lp, out);
}